// Round 5
// baseline (255.545 us; speedup 1.0000x reference)
//
#include <hip/hip_runtime.h>

#define H 1024
#define E 64
#define BT 64
#define THETA 2e-4f    // relative p-gap risk threshold (~= logit gap)

typedef __attribute__((ext_vector_type(4)))  float        f4;
typedef __attribute__((ext_vector_type(4)))  unsigned int u4;
typedef __attribute__((ext_vector_type(8)))  short        s8v;

__device__ __forceinline__ s8v as_s8(u4 v) { union { u4 u; s8v s; } c; c.u = v; return c.s; }

// Split 8 fp32 (two f4, k-ascending) into bf16 hi (RNE) + bf16 lo (trunc of
// exact residual), packed k-pairs little-endian into 4 dwords each.
__device__ __forceinline__ void split_octet(const f4 a, const f4 b, u4& hi, u4& lo) {
    float f[8] = {a.x, a.y, a.z, a.w, b.x, b.y, b.z, b.w};
    unsigned v[8], l[8];
    #pragma unroll
    for (int i = 0; i < 8; ++i) {
        unsigned u = __float_as_uint(f[i]);
        v[i] = u + 0x7FFFu + ((u >> 16) & 1u);            // RNE to bf16 in [31:16]
        float hf = __uint_as_float(v[i] & 0xFFFF0000u);   // hi as fp32
        l[i] = __float_as_uint(f[i] - hf);                // exact residual
    }
    hi.x = (v[0] >> 16) | (v[1] & 0xFFFF0000u);
    hi.y = (v[2] >> 16) | (v[3] & 0xFFFF0000u);
    hi.z = (v[4] >> 16) | (v[5] & 0xFFFF0000u);
    hi.w = (v[6] >> 16) | (v[7] & 0xFFFF0000u);
    lo.x = (l[0] >> 16) | (l[1] & 0xFFFF0000u);
    lo.y = (l[2] >> 16) | (l[3] & 0xFFFF0000u);
    lo.z = (l[4] >> 16) | (l[5] & 0xFFFF0000u);
    lo.w = (l[6] >> 16) | (l[7] & 0xFFFF0000u);
}

// =====================================================================
// Pass A: 64 tok x 64 exp per block. K-chunks of 32, double-buffered
// LDS of bf16 hi/lo operand fragments stored in exact frag-read order
// ([16-row group][k-octet][row] u4 — m97 pattern, conflict-free).
// 16x16x32 bf16 MFMA builtin (HW-verified A/B/C layouts, compiler
// hazard handling). 3 MFMA chains: hi*hi, lo*hi, hi*lo. Register
// prefetch keeps global loads in flight across the barrier.
// LDS u4 map per buffer (1024 u4): h_hi[0,256) h_lo[256,512)
//   w_hi[512,768) w_lo[768,1024); slot = ((row>>4)*4 + oct)*16 + (row&15)
// tail floats: S[64][68] @0, recip @4352, hist @4416, pi3 @4480
// =====================================================================
__global__ __launch_bounds__(256, 4)
void gate_main(const float* __restrict__ hs, const float* __restrict__ wt,
               float* __restrict__ out, float* __restrict__ pi_ws,
               float* __restrict__ ce_ws, unsigned int* __restrict__ risk_cnt,
               unsigned int* __restrict__ risk_list, unsigned int risk_cap,
               int n_tokens) {
    __shared__ float smem[8192];                  // 32 KB
    const int t = threadIdx.x;
    const int wave = t >> 6, lane = t & 63;
    const int tok_base = blockIdx.x * BT;

    // staging mapping: thread -> (row 0..63, k-octet 0..3)
    const int row_s = t >> 2, o = t & 3;
    const int wslot = ((row_s >> 4) * 4 + o) * 16 + (row_s & 15);
    const f4* hs4 = (const f4*)hs;
    const f4* wt4 = (const f4*)wt;
    const size_t gh = (size_t)(tok_base + row_s) * 256 + o * 2;
    const size_t gw = (size_t)row_s * 256 + o * 2;

    // mfma mapping: wave -> 32x32 quadrant, 2x2 of 16x16 tiles
    const int tokT = wave >> 1, expT = wave & 1;
    const int fa = (lane >> 4) * 16 + (lane & 15);    // within-group u4 offset

    f4 acch[2][2] = {};                           // hi*hi
    f4 accl[2][2] = {};                           // lo*hi + hi*lo
    f4 ph0 = hs4[gh], ph1 = hs4[gh + 1];
    f4 pw0 = wt4[gw], pw1 = wt4[gw + 1];

    for (int c = 0; c < 32; ++c) {
        u4* wb = (u4*)smem + (c & 1) * 1024;
        u4 hhi, hlo, whi, wlo;
        split_octet(ph0, ph1, hhi, hlo);
        split_octet(pw0, pw1, whi, wlo);
        wb[wslot]       = hhi;
        wb[256 + wslot] = hlo;
        wb[512 + wslot] = whi;
        wb[768 + wslot] = wlo;
        if (c < 31) {                              // prefetch next chunk
            ph0 = hs4[gh + (size_t)(c + 1) * 8];
            ph1 = hs4[gh + (size_t)(c + 1) * 8 + 1];
            pw0 = wt4[gw + (size_t)(c + 1) * 8];
            pw1 = wt4[gw + (size_t)(c + 1) * 8 + 1];
        }
        __syncthreads();                           // LDS writes visible
        const u4* rb = (const u4*)smem + (c & 1) * 1024;
        u4 ah[2], al[2], bh[2], bl[2];
        #pragma unroll
        for (int g = 0; g < 2; ++g) {
            ah[g] = rb[      (tokT * 2 + g) * 64 + fa];
            al[g] = rb[256 + (tokT * 2 + g) * 64 + fa];
            bh[g] = rb[512 + (expT * 2 + g) * 64 + fa];
            bl[g] = rb[768 + (expT * 2 + g) * 64 + fa];
        }
        #pragma unroll
        for (int tg = 0; tg < 2; ++tg)
            #pragma unroll
            for (int eg = 0; eg < 2; ++eg) {
                acch[tg][eg] = __builtin_amdgcn_mfma_f32_16x16x32_bf16(
                    as_s8(ah[tg]), as_s8(bh[eg]), acch[tg][eg], 0, 0, 0);
                accl[tg][eg] = __builtin_amdgcn_mfma_f32_16x16x32_bf16(
                    as_s8(al[tg]), as_s8(bh[eg]), accl[tg][eg], 0, 0, 0);
                accl[tg][eg] = __builtin_amdgcn_mfma_f32_16x16x32_bf16(
                    as_s8(ah[tg]), as_s8(bl[eg]), accl[tg][eg], 0, 0, 0);
            }
    }
    __syncthreads();                               // S region overlaps buffers

    // ---- fold + scatter logits to S[64][68]; C/D (m89-verified):
    //      col = lane&15, row = (lane>>4)*4 + reg ----
    float* S = smem;
    float* recip = smem + 4352;
    float* hist  = smem + 4416;
    float* pi3   = smem + 4480;
    #pragma unroll
    for (int tg = 0; tg < 2; ++tg)
        #pragma unroll
        for (int eg = 0; eg < 2; ++eg)
            #pragma unroll
            for (int i = 0; i < 4; ++i) {
                const int tok = tokT * 32 + tg * 16 + (lane >> 4) * 4 + i;
                const int e   = expT * 32 + eg * 16 + (lane & 15);
                S[tok * 68 + e] = acch[tg][eg][i] + accl[tg][eg][i];
            }
    if (t < 64) hist[t] = 0.f;
    __syncthreads();

    f4* S4 = (f4*)smem;                            // row stride 17 f4

    // ---- p = exp(l - m) in-place, 4 threads per token ----
    {
        const int tok = t >> 2, q = t & 3;
        f4 v[4];
        #pragma unroll
        for (int c = 0; c < 4; ++c) v[c] = S4[tok * 17 + q * 4 + c];
        float m = v[0].x;
        #pragma unroll
        for (int c = 0; c < 4; ++c)
            m = fmaxf(m, fmaxf(fmaxf(v[c].x, v[c].y), fmaxf(v[c].z, v[c].w)));
        m = fmaxf(m, __shfl_xor(m, 1, 64));
        m = fmaxf(m, __shfl_xor(m, 2, 64));
        float lsum = 0.f;
        #pragma unroll
        for (int c = 0; c < 4; ++c) {
            v[c].x = __expf(v[c].x - m); v[c].y = __expf(v[c].y - m);
            v[c].z = __expf(v[c].z - m); v[c].w = __expf(v[c].w - m);
            lsum += (v[c].x + v[c].y) + (v[c].z + v[c].w);
        }
        #pragma unroll
        for (int c = 0; c < 4; ++c) S4[tok * 17 + q * 4 + c] = v[c];
        lsum += __shfl_xor(lsum, 1, 64);
        lsum += __shfl_xor(lsum, 2, 64);
        if (q == 0) recip[tok] = 1.0f / lsum;
    }
    __syncthreads();

    // ---- SEL (one wave, thread-per-token) + pi partials (other waves) ----
    const int selw = blockIdx.x & 3;
    if (wave == selw) {
        const int tok = lane;
        const int tok_g = tok_base + tok;
        float val[9]; int idx[9];
        #pragma unroll
        for (int r = 0; r < 9; ++r) { val[r] = -1.f; idx[r] = 0; }
        #pragma unroll
        for (int c = 0; c < 16; ++c) {
            f4 v = S4[tok * 17 + c];
            float e4[4] = {v.x, v.y, v.z, v.w};
            #pragma unroll
            for (int u = 0; u < 4; ++u) {
                float cv = e4[u]; int ci = c * 4 + u;
                #pragma unroll
                for (int r = 0; r < 9; ++r) {
                    const bool g = cv > val[r];    // strict: stream order = stable ties
                    const float tv = val[r]; const int ti = idx[r];
                    val[r] = g ? cv : tv;  idx[r] = g ? ci : ti;
                    cv = g ? tv : cv;      ci = g ? ti : ci;
                }
            }
        }
        const float s8 = ((val[0] + val[1]) + (val[2] + val[3]))
                       + ((val[4] + val[5]) + (val[6] + val[7]));
        const float wsum = s8 + 1e-20f;
        f4* out4 = (f4*)out;
        f4 ov;
        ov.x = (float)idx[0]; ov.y = (float)idx[1]; ov.z = (float)idx[2]; ov.w = (float)idx[3];
        out4[(size_t)tok_g * 2] = ov;
        ov.x = (float)idx[4]; ov.y = (float)idx[5]; ov.z = (float)idx[6]; ov.w = (float)idx[7];
        out4[(size_t)tok_g * 2 + 1] = ov;
        const size_t wb2 = (size_t)n_tokens * 2;
        ov.x = val[0] / wsum; ov.y = val[1] / wsum; ov.z = val[2] / wsum; ov.w = val[3] / wsum;
        out4[wb2 + (size_t)tok_g * 2] = ov;
        ov.x = val[4] / wsum; ov.y = val[5] / wsum; ov.z = val[6] / wsum; ov.w = val[7] / wsum;
        out4[wb2 + (size_t)tok_g * 2 + 1] = ov;
        #pragma unroll
        for (int r = 0; r < 8; ++r) atomicAdd(&hist[idx[r]], 1.0f);
        float ming = 1e30f;
        #pragma unroll
        for (int r = 0; r < 8; ++r)
            ming = fminf(ming, (val[r] - val[r + 1]) / fmaxf(val[r], 1e-30f));
        if (ming < THETA) {
            unsigned int pos = atomicAdd(risk_cnt, 1u);
            if (pos < risk_cap) risk_list[pos] = (unsigned int)tok_g;
        }
    } else {
        const int third = ((wave - selw) & 3) - 1;        // 0..2
        const int e = lane;
        const int t0 = third * 21;
        const int t1 = (third == 2) ? 64 : (t0 + 21);
        float part = 0.f;
        for (int tok = t0; tok < t1; ++tok)
            part = fmaf(S[tok * 68 + e], recip[tok], part);
        pi3[third * 64 + e] = part;
    }
    __syncthreads();
    if (t < 64)       atomicAdd(&pi_ws[t], pi3[t] + pi3[64 + t] + pi3[128 + t]);
    else if (t < 128) atomicAdd(&ce_ws[t - 64], hist[t - 64]);
}

// =====================================================================
// Pass B: fp64 recompute of risky tokens (exact ranking).
// =====================================================================
__global__ __launch_bounds__(256)
void gate_fixup(const float* __restrict__ hs, const float* __restrict__ wt,
                float* __restrict__ out, const unsigned int* __restrict__ risk_cnt,
                const unsigned int* __restrict__ risk_list, unsigned int risk_cap,
                int n_tokens) {
    __shared__ float hrow[H];
    __shared__ double red[256];
    unsigned int cnt = *risk_cnt;
    if (cnt > risk_cap) cnt = risk_cap;
    const int t = threadIdx.x;

    for (unsigned int u = blockIdx.x; u < cnt; u += gridDim.x) {
        const int tok = (int)risk_list[u];
        ((float4*)hrow)[t] = ((const float4*)(hs + (size_t)tok * H))[t];
        __syncthreads();

        const int e = t >> 2, sl = t & 3;
        const float4* wp = (const float4*)wt + (size_t)e * 256;
        const float4* hp = (const float4*)hrow;
        double acc = 0.0;
        #pragma unroll 8
        for (int k4 = 0; k4 < 64; ++k4) {
            float4 wv = wp[k4 * 4 + sl];
            float4 hv = hp[k4 * 4 + sl];
            acc = fma((double)wv.x, (double)hv.x, acc);
            acc = fma((double)wv.y, (double)hv.y, acc);
            acc = fma((double)wv.z, (double)hv.z, acc);
            acc = fma((double)wv.w, (double)hv.w, acc);
        }
        red[t] = acc;
        __syncthreads();

        if (t < 64) {
            const int lane = t;
            double lg = red[t * 4] + red[t * 4 + 1] + red[t * 4 + 2] + red[t * 4 + 3];
            double m = lg;
            #pragma unroll
            for (int off = 32; off > 0; off >>= 1) {
                double o = __shfl_xor(m, off, 64);
                m = (o > m) ? o : m;
            }
            const double p = exp(lg - m);
            double v = lg, psum = 0.0, mypv = 0.0;
            int myidx = 0;
            for (int r = 0; r < 8; ++r) {
                double bv = v; int bi = lane;
                #pragma unroll
                for (int off = 32; off > 0; off >>= 1) {
                    double ov = __shfl_xor(bv, off, 64);
                    int    oi = __shfl_xor(bi, off, 64);
                    if (ov > bv || (ov == bv && oi < bi)) { bv = ov; bi = oi; }
                }
                double pw = __shfl(p, bi, 64);
                psum += pw;
                if (lane == r) { myidx = bi; mypv = pw; }
                if (lane == bi) v = -1e300;
            }
            const double wsum = psum + 1e-20;
            if (lane < 8) {
                out[(size_t)tok * 8 + lane] = (float)myidx;
                out[(size_t)n_tokens * 8 + (size_t)tok * 8 + lane] = (float)(mypv / wsum);
            }
        }
        __syncthreads();
    }
}

// =====================================================================
// Pass C: finalize aux loss.
// =====================================================================
__global__ void gate_aux(const float* __restrict__ pi_ws, const float* __restrict__ ce_ws,
                         float* __restrict__ out, int n_tokens) {
    const int lane = threadIdx.x;                 // 64 threads
    double pi = (double)pi_ws[lane] / (double)n_tokens;
    double ce = (double)ce_ws[lane] / ((double)n_tokens * 8.0);
    double term = pi * ce * 64.0;
    #pragma unroll
    for (int off = 32; off > 0; off >>= 1) term += __shfl_xor(term, off, 64);
    if (lane == 0) out[(size_t)n_tokens * 16] = (float)(term * 0.01);
}

extern "C" void kernel_launch(void* const* d_in, const int* in_sizes, int n_in,
                              void* d_out, int out_size, void* d_ws, size_t ws_size,
                              hipStream_t stream) {
    const float* hs = (const float*)d_in[0];
    const float* wt = (const float*)d_in[1];
    float* out = (float*)d_out;
    const int n_tokens = in_sizes[0] / H;         // 32768

    float* pi_ws = (float*)d_ws;
    float* ce_ws = (float*)((char*)d_ws + 256);
    unsigned int* risk_cnt  = (unsigned int*)((char*)d_ws + 512);
    unsigned int* risk_list = (unsigned int*)((char*)d_ws + 1024);
    unsigned int risk_cap = (unsigned int)((ws_size > 1024 ? (ws_size - 1024) : 0) / 4);
    if (risk_cap > (unsigned int)n_tokens) risk_cap = (unsigned int)n_tokens;

    size_t zbytes = ws_size < 1024 ? ws_size : 1024;
    hipMemsetAsync(d_ws, 0, zbytes, stream);

    gate_main<<<n_tokens / BT, 256, 0, stream>>>(hs, wt, out, pi_ws, ce_ws,
                                                 risk_cnt, risk_list, risk_cap, n_tokens);
    gate_fixup<<<256, 256, 0, stream>>>(hs, wt, out, risk_cnt, risk_list, risk_cap, n_tokens);
    gate_aux<<<1, 64, 0, stream>>>(pi_ws, ce_ws, out, n_tokens);
}